// Round 7
// baseline (394.278 us; speedup 1.0000x reference)
//
#include <hip/hip_runtime.h>

#define S 2048
#define H 1024
#define NH 16
#define NKV 8
#define HD 64
#define NE 8
#define ID 2048

typedef short bf16x8 __attribute__((ext_vector_type(8)));
typedef short bf16x4 __attribute__((ext_vector_type(4)));
typedef float f32x4 __attribute__((ext_vector_type(4)));

__device__ __forceinline__ unsigned short f2bf(float f) {
  unsigned u = __builtin_bit_cast(unsigned, f);
  u += 0x7FFFu + ((u >> 16) & 1u);
  return (unsigned short)(u >> 16);
}
__device__ __forceinline__ float bf2f(unsigned short h) {
  unsigned u = ((unsigned)h) << 16;
  return __builtin_bit_cast(float, u);
}

typedef const __attribute__((address_space(1))) unsigned int gas_u32;
typedef __attribute__((address_space(3))) unsigned int las_u32;
// direct global->LDS DMA, 16B per lane; LDS dest = wave-uniform base + lane*16
__device__ __forceinline__ void gload16(const unsigned short* g, unsigned short* l) {
  __builtin_amdgcn_global_load_lds((gas_u32*)g, (las_u32*)l, 16, 0, 0);
}

// ---------------- RMSNorm ----------------
// OUTM 0: write hi+lo bf16 planes. OUTM 1: write f32 + hi bf16.
template <int OUTM>
__global__ __launch_bounds__(256) void rmsnorm_kernel(const float* __restrict__ x,
                                                      const float* __restrict__ wgt,
                                                      float* __restrict__ outf,
                                                      unsigned short* __restrict__ ohi,
                                                      unsigned short* __restrict__ olo) {
  int row = blockIdx.x;
  const float* xr = x + (size_t)row * H;
  int tid = threadIdx.x;
  float v[4];
  float ss = 0.f;
#pragma unroll
  for (int i = 0; i < 4; i++) {
    v[i] = xr[tid + i * 256];
    ss += v[i] * v[i];
  }
#pragma unroll
  for (int off = 1; off < 64; off <<= 1) ss += __shfl_xor(ss, off);
  __shared__ float part[4];
  if ((tid & 63) == 0) part[tid >> 6] = ss;
  __syncthreads();
  float tot = part[0] + part[1] + part[2] + part[3];
  float r = rsqrtf(tot * (1.f / H) + 1e-6f);
#pragma unroll
  for (int i = 0; i < 4; i++) {
    int c = tid + i * 256;
    float vv = v[i] * r * wgt[c];
    size_t o = (size_t)row * H + c;
    if (OUTM == 0) {
      unsigned short h_ = f2bf(vv);
      ohi[o] = h_;
      olo[o] = f2bf(vv - bf2f(h_));
    } else {
      outf[o] = vv;
      ohi[o] = f2bf(vv);
    }
  }
}

// ---------------- transpose-convert: src f32 [K][N] -> dst bf16 [N][K] ----------------
template <bool LO>
__global__ __launch_bounds__(256) void tconv_kernel(const float* __restrict__ src,
                                                    unsigned short* __restrict__ hi,
                                                    unsigned short* __restrict__ lo,
                                                    int K, int N, long long sStride,
                                                    long long dStride) {
  int nt = blockIdx.x, kt = blockIdx.y, b = blockIdx.z;
  src += (size_t)b * sStride;
  hi += (size_t)b * dStride;
  if (LO) lo += (size_t)b * dStride;
  __shared__ float tile[64][65];
  int tid = threadIdx.x;
  int r = tid >> 2, cs = (tid & 3) * 16;
  const float* s0 = src + (size_t)(kt * 64 + r) * N + nt * 64 + cs;
#pragma unroll
  for (int i = 0; i < 16; i += 4) {
    float4 a = *(const float4*)(s0 + i);
    tile[r][cs + i] = a.x;
    tile[r][cs + i + 1] = a.y;
    tile[r][cs + i + 2] = a.z;
    tile[r][cs + i + 3] = a.w;
  }
  __syncthreads();
  int n = nt * 64 + r;
  size_t dbase = (size_t)n * K + kt * 64 + cs;
  unsigned short th[16], tl[16];
#pragma unroll
  for (int i = 0; i < 16; i++) {
    float vv = tile[cs + i][r];
    unsigned short h_ = f2bf(vv);
    th[i] = h_;
    if (LO) tl[i] = f2bf(vv - bf2f(h_));
  }
  *(bf16x8*)(hi + dbase) = *(bf16x8*)&th[0];
  *(bf16x8*)(hi + dbase + 8) = *(bf16x8*)&th[8];
  if (LO) {
    *(bf16x8*)(lo + dbase) = *(bf16x8*)&tl[0];
    *(bf16x8*)(lo + dbase + 8) = *(bf16x8*)&tl[8];
  }
}

// ---------------- MFMA GEMM, 128x64 tile, BK=64, gload_lds + XOR swizzle ----------------
// MODE 0: QKV   A=h hi/lo [M][K], B=wqkvT hi/lo [N][K], 3-term split, C=qkv f32
// MODE 1: OPROJ same + resid, dual store (x2 and out)
// MODE 2: MOEA  A=t_bf gathered (tile table grid), Bh=w1T Bl=w3T, silu(g1)*g3 -> G bf16
// MODE 3: MOEB  A=G (tile table grid), B=w2T, atomicAdd out += v*wgt
template <int MODE>
__global__ __launch_bounds__(256) void gemm_kernel(
    const unsigned short* __restrict__ Ah, const unsigned short* __restrict__ Al,
    const unsigned short* __restrict__ Bh, const unsigned short* __restrict__ Bl,
    float* __restrict__ C, float* __restrict__ C2, unsigned short* __restrict__ Gout,
    const float* __restrict__ resid, const int* __restrict__ idx,
    const float* __restrict__ wgt, const int* __restrict__ cnt,
    const int* __restrict__ offs, const int* __restrict__ tmap, int N, int K) {
  int n0 = blockIdx.x * 64, m0, e = 0;
  int ce = 0, gbase = 0;
  if (MODE >= 2) {
    int ntiles = tmap[63];
    if ((int)blockIdx.y >= ntiles) return;
    int packed = tmap[blockIdx.y];
    e = packed >> 16;
    m0 = (packed & 0xffff) * 128;
    ce = cnt[e];
    gbase = offs[e];
  } else {
    m0 = blockIdx.y * 128;
  }
  const unsigned short* bhp = Bh;
  const unsigned short* blp = Bl;
  if (MODE == 2) {
    bhp += (size_t)e * 2048 * 1024;
    blp += (size_t)e * 2048 * 1024;
  }
  if (MODE == 3) bhp += (size_t)e * 1024 * 2048;

  __shared__ __align__(16) unsigned short tAh[128 * 64];
  __shared__ __align__(16) unsigned short tAl[128 * 64];
  __shared__ __align__(16) unsigned short tBh[64 * 64];
  __shared__ __align__(16) unsigned short tBl[64 * 64];

  int tid = threadIdx.x, w = tid >> 6, lane = tid & 63;
  int lr = lane & 15, g = lane >> 4;
  int rloc = lane >> 3, slotg = (lane & 7) ^ rloc;
  int wm = w >> 1, wn = w & 1;

  // per-chunk per-lane source element offsets (k0=0); inverse-swizzled slot
  unsigned aOff[4], bOff[2];
#pragma unroll
  for (int cc = 0; cc < 4; cc++) {
    int rr = w * 32 + cc * 8 + rloc;  // tile-local row 0..127
    if (MODE == 2) {
      int gr = m0 + rr;
      if (gr > ce - 1) gr = ce - 1;
      int tok = idx[e * S + gr];
      aOff[cc] = (unsigned)(tok * K + slotg * 8);
    } else if (MODE == 3) {
      int gr = gbase + m0 + rr;
      if (gr > 4095) gr = 4095;
      aOff[cc] = (unsigned)(gr * K + slotg * 8);
    } else {
      aOff[cc] = (unsigned)((m0 + rr) * K + slotg * 8);
    }
  }
#pragma unroll
  for (int cc = 0; cc < 2; cc++) {
    int rr = w * 16 + cc * 8 + rloc;  // tile-local n-row 0..63
    bOff[cc] = (unsigned)((n0 + rr) * K + slotg * 8);
  }

  f32x4 acc[4][2], acc2[4][2];
#pragma unroll
  for (int i = 0; i < 4; i++)
#pragma unroll
    for (int j = 0; j < 2; j++) {
      acc[i][j] = f32x4{0.f, 0.f, 0.f, 0.f};
      if (MODE == 2) acc2[i][j] = f32x4{0.f, 0.f, 0.f, 0.f};
    }

  for (int k0 = 0; k0 < K; k0 += 64) {
    __syncthreads();
#pragma unroll
    for (int cc = 0; cc < 4; cc++) {
      int cb = (w * 4 + cc) * 512;
      gload16(Ah + aOff[cc] + k0, &tAh[cb]);
      if (MODE <= 1) gload16(Al + aOff[cc] + k0, &tAl[cb]);
    }
#pragma unroll
    for (int cc = 0; cc < 2; cc++) {
      int cb = (w * 2 + cc) * 512;
      gload16(bhp + bOff[cc] + k0, &tBh[cb]);
      if (MODE <= 2) gload16(blp + bOff[cc] + k0, &tBl[cb]);
    }
    __syncthreads();
    bf16x8 fah[4][2], fal[4][2];
#pragma unroll
    for (int i = 0; i < 4; i++) {
      int ar = wm * 64 + i * 16 + lr;
#pragma unroll
      for (int kk = 0; kk < 2; kk++) {
        int off = ar * 64 + (((kk * 4 + g) ^ (ar & 7)) * 8);
        fah[i][kk] = *(const bf16x8*)&tAh[off];
        if (MODE <= 1) fal[i][kk] = *(const bf16x8*)&tAl[off];
      }
    }
#pragma unroll
    for (int j = 0; j < 2; j++) {
      int br = wn * 32 + j * 16 + lr;
      bf16x8 fbh[2], fbl[2];
#pragma unroll
      for (int kk = 0; kk < 2; kk++) {
        int off = br * 64 + (((kk * 4 + g) ^ (br & 7)) * 8);
        fbh[kk] = *(const bf16x8*)&tBh[off];
        if (MODE <= 2) fbl[kk] = *(const bf16x8*)&tBl[off];
      }
#pragma unroll
      for (int i = 0; i < 4; i++) {
#pragma unroll
        for (int kk = 0; kk < 2; kk++) {
          acc[i][j] = __builtin_amdgcn_mfma_f32_16x16x32_bf16(fah[i][kk], fbh[kk], acc[i][j], 0, 0, 0);
          if (MODE <= 1) {
            acc[i][j] = __builtin_amdgcn_mfma_f32_16x16x32_bf16(fah[i][kk], fbl[kk], acc[i][j], 0, 0, 0);
            acc[i][j] = __builtin_amdgcn_mfma_f32_16x16x32_bf16(fal[i][kk], fbh[kk], acc[i][j], 0, 0, 0);
          }
          if (MODE == 2)
            acc2[i][j] = __builtin_amdgcn_mfma_f32_16x16x32_bf16(fah[i][kk], fbl[kk], acc2[i][j], 0, 0, 0);
        }
      }
    }
  }
  // epilogue
#pragma unroll
  for (int i = 0; i < 4; i++)
#pragma unroll
    for (int j = 0; j < 2; j++)
#pragma unroll
      for (int r = 0; r < 4; r++) {
        int grow = wm * 64 + i * 16 + g * 4 + r;
        int gcol = n0 + wn * 32 + j * 16 + lr;
        float v = acc[i][j][r];
        if (MODE == 0) {
          C[(size_t)(m0 + grow) * N + gcol] = v;
        } else if (MODE == 1) {
          float o = v + resid[(size_t)(m0 + grow) * N + gcol];
          C[(size_t)(m0 + grow) * N + gcol] = o;
          C2[(size_t)(m0 + grow) * N + gcol] = o;
        } else if (MODE == 2) {
          if (m0 + grow < ce) {
            float g3 = acc2[i][j][r];
            float sg = v / (1.f + __expf(-v));
            Gout[(size_t)(gbase + m0 + grow) * 2048 + gcol] = f2bf(sg * g3);
          }
        } else {
          if (m0 + grow < ce) {
            int tok = idx[e * S + m0 + grow];
            float wv = wgt[e * S + m0 + grow];
            atomicAdd(&C[(size_t)tok * 1024 + gcol], v * wv);
          }
        }
      }
}

// ---------------- RoPE: qkv f32 -> q hi/lo (x0.125), k hi/lo planes ----------------
__global__ __launch_bounds__(256) void rope_kernel(
    const float* __restrict__ qkv, const float* __restrict__ sinb,
    const float* __restrict__ cosb, const int* __restrict__ pos,
    unsigned short* __restrict__ qhi, unsigned short* __restrict__ qlo,
    unsigned short* __restrict__ khi, unsigned short* __restrict__ klo) {
  int i = blockIdx.x * 256 + threadIdx.x;
  int d = i & 31;
  int s = (i >> 5) & 2047;
  int hh = i >> 16;  // 0..23
  int p = pos[s];
  float c0 = cosb[p * HD + d], c1 = cosb[p * HD + d + 32];
  float s0 = sinb[p * HD + d], s1 = sinb[p * HD + d + 32];
  const float* srcb = qkv + (size_t)s * 2048;
  if (hh < NH) {
    float x0 = srcb[hh * HD + d], x1 = srcb[hh * HD + d + 32];
    float r0 = (x0 * c0 - x1 * s0) * 0.125f;
    float r1 = (x1 * c1 + x0 * s1) * 0.125f;
    size_t o = ((size_t)hh * S + s) * HD + d;
    unsigned short h0 = f2bf(r0), h1 = f2bf(r1);
    qhi[o] = h0;
    qlo[o] = f2bf(r0 - bf2f(h0));
    qhi[o + 32] = h1;
    qlo[o + 32] = f2bf(r1 - bf2f(h1));
  } else {
    int hk = hh - NH;
    float x0 = srcb[1024 + hk * HD + d], x1 = srcb[1024 + hk * HD + d + 32];
    float r0 = x0 * c0 - x1 * s0;
    float r1 = x1 * c1 + x0 * s1;
    size_t o = ((size_t)hk * S + s) * HD + d;
    unsigned short h0 = f2bf(r0), h1 = f2bf(r1);
    khi[o] = h0;
    klo[o] = f2bf(r0 - bf2f(h0));
    khi[o + 32] = h1;
    klo[o + 32] = f2bf(r1 - bf2f(h1));
  }
}

// ---------------- V transpose: qkv v-cols -> vT[hk][d][s] hi/lo bf16 ----------------
__global__ __launch_bounds__(256) void vtrans_kernel(const float* __restrict__ qkv,
                                                     unsigned short* __restrict__ vThi,
                                                     unsigned short* __restrict__ vTlo) {
  int st = blockIdx.x, hk = blockIdx.y;
  __shared__ float tile[64][65];
  int tid = threadIdx.x;
  int r = tid >> 2, seg = (tid & 3) * 16;
  const float* src = qkv + (size_t)(st * 64 + r) * 2048 + 1536 + hk * HD + seg;
#pragma unroll
  for (int i = 0; i < 16; i += 4) {
    float4 a = *(const float4*)(src + i);
    tile[r][seg + i] = a.x;
    tile[r][seg + i + 1] = a.y;
    tile[r][seg + i + 2] = a.z;
    tile[r][seg + i + 3] = a.w;
  }
  __syncthreads();
  int d = tid >> 2, ss = (tid & 3) * 16;
  unsigned short th[16], tl[16];
#pragma unroll
  for (int i = 0; i < 16; i++) {
    float vv = tile[ss + i][d];
    unsigned short h_ = f2bf(vv);
    th[i] = h_;
    tl[i] = f2bf(vv - bf2f(h_));
  }
  size_t dst = ((size_t)hk * HD + d) * S + st * 64 + ss;
  *(bf16x8*)(vThi + dst) = *(bf16x8*)&th[0];
  *(bf16x8*)(vThi + dst + 8) = *(bf16x8*)&th[8];
  *(bf16x8*)(vTlo + dst) = *(bf16x8*)&tl[0];
  *(bf16x8*)(vTlo + dst + 8) = *(bf16x8*)&tl[8];
}

// ---------------- flash attention (MFMA, pre-split bf16, kv-split partials) ----------------
// grid (32 qt, 16 heads, 2 kv-splits). Writes unnormalized f32 partials (po,pm,pl).
// LDS exactly 40 KB -> 4 blocks/CU. P buffer time-shared between hi and lo (per-wave).
#define FSWZ(row, byteoff) ((byteoff) ^ (((row) & 7) << 4))

__global__ __launch_bounds__(256) void flash_kernel(
    const unsigned short* __restrict__ qhi, const unsigned short* __restrict__ qlo,
    const unsigned short* __restrict__ khip, const unsigned short* __restrict__ klop,
    const unsigned short* __restrict__ vthip, const unsigned short* __restrict__ vtlop,
    const float* __restrict__ amask, float* __restrict__ po, float* __restrict__ pm,
    float* __restrict__ pl) {
  int qt = (int)gridDim.x - 1 - (int)blockIdx.x;  // long blocks first
  int head = blockIdx.y, z = blockIdx.z;
  int tid = threadIdx.x;
  int w = tid >> 6, lane = tid & 63;
  int lr = lane & 15, g = lane >> 4;
  int rloc = lane >> 3, slotg = (lane & 7) ^ rloc;

  __shared__ __align__(16) unsigned short Khi[64 * 64];
  __shared__ __align__(16) unsigned short Klo[64 * 64];
  __shared__ __align__(16) unsigned short Vhi[64 * 64];
  __shared__ __align__(16) unsigned short Vlo[64 * 64];
  __shared__ __align__(16) unsigned short Pbuf[4][16 * 64];

  int qrow = qt * 64 + w * 16 + lr;
  bf16x8 qh[2], ql[2];
  {
    const unsigned short* qb = qhi + ((size_t)head * S + qrow) * HD;
    const unsigned short* qb2 = qlo + ((size_t)head * S + qrow) * HD;
    qh[0] = *(const bf16x8*)(qb + g * 8);
    qh[1] = *(const bf16x8*)(qb + 32 + g * 8);
    ql[0] = *(const bf16x8*)(qb2 + g * 8);
    ql[1] = *(const bf16x8*)(qb2 + 32 + g * 8);
  }

  f32x4 oacc[4];
#pragma unroll
  for (int dg = 0; dg < 4; dg++) oacc[dg] = f32x4{0.f, 0.f, 0.f, 0.f};
  float m = -1e30f, l = 0.f;

  const unsigned short* kbh = khip + (size_t)(head >> 1) * S * HD;
  const unsigned short* kbl = klop + (size_t)(head >> 1) * S * HD;
  const unsigned short* vbh = vthip + (size_t)(head >> 1) * HD * S;
  const unsigned short* vbl = vtlop + (size_t)(head >> 1) * HD * S;
  char* pbase = (char*)Pbuf[w];

  int nblk = qt + 1;
  int b0 = (z * nblk) >> 1, b1 = ((z + 1) * nblk) >> 1;

  for (int kb = b0; kb < b1; kb++) {
    int kv0 = kb * 64;
    __syncthreads();
#pragma unroll
    for (int cc = 0; cc < 2; cc++) {
      int c = w * 2 + cc;
      int r = c * 8 + rloc;
      gload16(kbh + (size_t)(kv0 + r) * HD + slotg * 8, &Khi[c * 512]);
      gload16(kbl + (size_t)(kv0 + r) * HD + slotg * 8, &Klo[c * 512]);
      gload16(vbh + (size_t)r * S + kv0 + slotg * 8, &Vhi[c * 512]);
      gload16(vbl + (size_t)r * S + kv0 + slotg * 8, &Vlo[c * 512]);
    }
    unsigned long long vm = __ballot(amask[kv0 + lane] > 0.f);
    __syncthreads();

    // ---- QK^T (S^T): lane -> q-row lr, kv = c*16 + 4*g + r ----
    f32x4 sacc[4];
#pragma unroll
    for (int c = 0; c < 4; c++) sacc[c] = f32x4{0.f, 0.f, 0.f, 0.f};
#pragma unroll
    for (int c = 0; c < 4; c++) {
#pragma unroll
      for (int kc = 0; kc < 2; kc++) {
        int row = c * 16 + lr;
        int bo = FSWZ(row, row * 128 + kc * 64 + g * 16);
        bf16x8 khf = *(const bf16x8*)((char*)Khi + bo);
        bf16x8 klf = *(const bf16x8*)((char*)Klo + bo);
        sacc[c] = __builtin_amdgcn_mfma_f32_16x16x32_bf16(khf, qh[kc], sacc[c], 0, 0, 0);
        sacc[c] = __builtin_amdgcn_mfma_f32_16x16x32_bf16(khf, ql[kc], sacc[c], 0, 0, 0);
        sacc[c] = __builtin_amdgcn_mfma_f32_16x16x32_bf16(klf, qh[kc], sacc[c], 0, 0, 0);
      }
    }
    // ---- mask + online softmax ----
    int qloc = w * 16 + lr;
    bool diag = (kb == qt);
    float tm = -1e30f;
#pragma unroll
    for (int c = 0; c < 4; c++) {
#pragma unroll
      for (int r = 0; r < 4; r++) {
        int kvloc = c * 16 + 4 * g + r;
        bool vis = ((vm >> kvloc) & 1ull) && (!diag || kvloc <= qloc);
        float sv = vis ? sacc[c][r] : -1e30f;
        sacc[c][r] = sv;
        tm = fmaxf(tm, sv);
      }
    }
    tm = fmaxf(tm, __shfl_xor(tm, 16));
    tm = fmaxf(tm, __shfl_xor(tm, 32));
    float newm = fmaxf(m, tm);
    float alpha = __expf(m - newm);
    float rs = 0.f;
#pragma unroll
    for (int c = 0; c < 4; c++) {
#pragma unroll
      for (int r = 0; r < 4; r++) {
        float p = __expf(sacc[c][r] - newm);
        sacc[c][r] = p;
        rs += p;
      }
    }
    rs += __shfl_xor(rs, 16);
    rs += __shfl_xor(rs, 32);
    m = newm;
    l = l * alpha + rs;
#pragma unroll
    for (int dg = 0; dg < 4; dg++) {
#pragma unroll
      for (int r = 0; r < 4; r++) oacc[dg][r] *= alpha;
    }
    // ---- P hi -> per-wave LDS, read frags, then P lo (time-shared buffer) ----
#pragma unroll
    for (int c = 0; c < 4; c++) {
      bf16x4 ph;
#pragma unroll
      for (int r = 0; r < 4; r++) ph[r] = (short)f2bf(sacc[c][r]);
      *(bf16x4*)(pbase + FSWZ(lr, lr * 128 + (c * 16 + 4 * g) * 2)) = ph;
    }
    bf16x8 pbh[2], pbl[2];
#pragma unroll
    for (int kc = 0; kc < 2; kc++)
      pbh[kc] = *(const bf16x8*)(pbase + FSWZ(lr, lr * 128 + kc * 64 + g * 16));
#pragma unroll
    for (int c = 0; c < 4; c++) {
      bf16x4 pl2;
#pragma unroll
      for (int r = 0; r < 4; r++) {
        float pv = sacc[c][r];
        pl2[r] = (short)f2bf(pv - bf2f(f2bf(pv)));
      }
      *(bf16x4*)(pbase + FSWZ(lr, lr * 128 + (c * 16 + 4 * g) * 2)) = pl2;
    }
#pragma unroll
    for (int kc = 0; kc < 2; kc++)
      pbl[kc] = *(const bf16x8*)(pbase + FSWZ(lr, lr * 128 + kc * 64 + g * 16));
    // ---- PV: O^T += V^T * P^T ----
#pragma unroll
    for (int dg = 0; dg < 4; dg++) {
#pragma unroll
      for (int kc = 0; kc < 2; kc++) {
        int row = dg * 16 + lr;
        int bo = FSWZ(row, row * 128 + kc * 64 + g * 16);
        bf16x8 vhf = *(const bf16x8*)((char*)Vhi + bo);
        bf16x8 vlf = *(const bf16x8*)((char*)Vlo + bo);
        oacc[dg] = __builtin_amdgcn_mfma_f32_16x16x32_bf16(vhf, pbh[kc], oacc[dg], 0, 0, 0);
        oacc[dg] = __builtin_amdgcn_mfma_f32_16x16x32_bf16(vhf, pbl[kc], oacc[dg], 0, 0, 0);
        oacc[dg] = __builtin_amdgcn_mfma_f32_16x16x32_bf16(vlf, pbh[kc], oacc[dg], 0, 0, 0);
      }
    }
  }

  // write unnormalized f32 partials
  size_t pb = (size_t)(qt * 16 + head) * 2 + z;
  int row = w * 16 + lr;
  if (g == 0) {
    pm[pb * 64 + row] = m;
    pl[pb * 64 + row] = l;
  }
  float* pob = po + pb * 4096 + (size_t)row * 64;
#pragma unroll
  for (int dg = 0; dg < 4; dg++) {
    float4 v4 = {oacc[dg][0], oacc[dg][1], oacc[dg][2], oacc[dg][3]};
    *(float4*)(pob + dg * 16 + 4 * g) = v4;
  }
}

// merge 2 kv-split partials -> o hi/lo bf16 planes
__global__ __launch_bounds__(256) void combine_kernel(const float* __restrict__ po,
                                                      const float* __restrict__ pm,
                                                      const float* __restrict__ pl,
                                                      unsigned short* __restrict__ ohi,
                                                      unsigned short* __restrict__ olo) {
  int qt = blockIdx.x, head = blockIdx.y;
  int r = threadIdx.x >> 2, dg = (threadIdx.x & 3) * 16;
  size_t base = (size_t)(qt * 16 + head) * 2;
  float m0v = pm[base * 64 + r], m1v = pm[(base + 1) * 64 + r];
  float l0 = pl[base * 64 + r], l1 = pl[(base + 1) * 64 + r];
  float M = fmaxf(m0v, m1v);
  float w0 = __expf(m0v - M), w1 = __expf(m1v - M);
  float inv = 1.f / (w0 * l0 + w1 * l1);
  const float* p0 = po + base * 4096 + (size_t)r * 64 + dg;
  const float* p1 = po + (base + 1) * 4096 + (size_t)r * 64 + dg;
  unsigned short th[16], tl[16];
#pragma unroll
  for (int i = 0; i < 16; i += 4) {
    float4 a = *(const float4*)(p0 + i);
    float4 b = *(const float4*)(p1 + i);
    float vv[4] = {(w0 * a.x + w1 * b.x) * inv, (w0 * a.y + w1 * b.y) * inv,
                   (w0 * a.z + w1 * b.z) * inv, (w0 * a.w + w1 * b.w) * inv};
#pragma unroll
    for (int j = 0; j < 4; j++) {
      unsigned short h_ = f2bf(vv[j]);
      th[i + j] = h_;
      tl[i + j] = f2bf(vv[j] - bf2f(h_));
    }
  }
  size_t ob = (size_t)(qt * 64 + r) * 1024 + head * 64 + dg;
  *(bf16x8*)(ohi + ob) = *(bf16x8*)&th[0];
  *(bf16x8*)(ohi + ob + 8) = *(bf16x8*)&th[8];
  *(bf16x8*)(olo + ob) = *(bf16x8*)&tl[0];
  *(bf16x8*)(olo + ob + 8) = *(bf16x8*)&tl[8];
}

// ---------------- router ----------------
__global__ __launch_bounds__(256) void router_kernel(const float* __restrict__ t,
                                                     const float* __restrict__ gw,
                                                     int* __restrict__ cnt,
                                                     int* __restrict__ idxb,
                                                     float* __restrict__ wgtb) {
  int tok = blockIdx.x * 4 + (threadIdx.x >> 6);
  int lane = threadIdx.x & 63;
  const float* tr = t + (size_t)tok * H;
  float acc[NE];
#pragma unroll
  for (int e = 0; e < NE; e++) acc[e] = 0.f;
#pragma unroll
  for (int i = 0; i < 16; i++) {
    float tv = tr[lane * 16 + i];
    const float* g = gw + (size_t)(lane * 16 + i) * NE;
#pragma unroll
    for (int e = 0; e < NE; e++) acc[e] += tv * g[e];
  }
#pragma unroll
  for (int off = 1; off < 64; off <<= 1) {
#pragma unroll
    for (int e = 0; e < NE; e++) acc[e] += __shfl_xor(acc[e], off);
  }
  if (lane == 0) {
    int e1 = 0;
#pragma unroll
    for (int e = 1; e < NE; e++)
      if (acc[e] > acc[e1]) e1 = e;
    int e2 = -1;
#pragma unroll
    for (int e = 0; e < NE; e++)
      if (e != e1 && (e2 < 0 || acc[e] > acc[e2])) e2 = e;
    float w1v = 1.f / (1.f + __expf(acc[e2] - acc[e1]));
    float w2v = 1.f - w1v;
    int p1 = atomicAdd(&cnt[e1], 1);
    idxb[e1 * S + p1] = tok;
    wgtb[e1 * S + p1] = w1v;
    int p2 = atomicAdd(&cnt[e2], 1);
    idxb[e2 * S + p2] = tok;
    wgtb[e2 * S + p2] = w2v;
  }
}

// prefix offsets + dense tile table: tmap[t] = (expert<<16) | m_tile, tmap[63] = count
__global__ void offsets_kernel(const int* __restrict__ cnt, int* __restrict__ offs,
                               int* __restrict__ tmap) {
  if (threadIdx.x == 0 && blockIdx.x == 0) {
    int a = 0, t = 0;
    for (int e = 0; e < NE; e++) {
      offs[e] = a;
      a += cnt[e];
      int nt = (cnt[e] + 127) >> 7;
      for (int i = 0; i < nt; i++) tmap[t++] = (e << 16) | i;
    }
    offs[NE] = a;
    tmap[63] = t;  // t <= 40
  }
}

// ---------------- launch ----------------
extern "C" void kernel_launch(void* const* d_in, const int* in_sizes, int n_in,
                              void* d_out, int out_size, void* d_ws, size_t ws_size,
                              hipStream_t stream) {
  const float* x = (const float*)d_in[0];
  const float* amask = (const float*)d_in[1];
  const int* pos = (const int*)d_in[2];
  const float* sinb = (const float*)d_in[3];
  const float* cosb = (const float*)d_in[4];
  const float* wq = (const float*)d_in[5];
  const float* wk = (const float*)d_in[6];
  const float* wv = (const float*)d_in[7];
  const float* wo = (const float*)d_in[8];
  const float* ln1 = (const float*)d_in[9];
  const float* ln2 = (const float*)d_in[10];
  const float* gw = (const float*)d_in[11];
  const float* w1 = (const float*)d_in[12];
  const float* w3 = (const float*)d_in[13];
  const float* w2 = (const float*)d_in[14];
  float* out = (float*)d_out;

  char* ws = (char*)d_ws;
  const size_t MB = 1024 * 1024;
  // persistent
  float* x2 = (float*)(ws + 0 * MB);                    // 8 MB
  unsigned short* t_bf = (unsigned short*)(ws + 8 * MB);  // 4 MB
  int* cnt = (int*)(ws + 12 * MB);
  int* offs = cnt + 16;
  int* tmap = cnt + 32;            // 64 ints
  int* idxb = cnt + 128;
  float* wgtb = (float*)(idxb + NE * S);
  // MoE region
  unsigned short* G = (unsigned short*)(ws + 13 * MB);    // 16 MB: 13-29
  unsigned short* w1T = (unsigned short*)(ws + 29 * MB);  // 32 MB: 29-61
  unsigned short* w3T = (unsigned short*)(ws + 61 * MB);  // 32 MB: 61-93
  unsigned short* w2T = (unsigned short*)(ws + 29 * MB);  // reuse after mode2
  // phase-1 overlays (dead before MoE tconvs run)
  float* qkv = (float*)(ws + 13 * MB);                       // 16 MB: 13-29 (dead by flash)
  float* po = (float*)(ws + 13 * MB);                        // 16 MB: flash partials (dead by mode2)
  unsigned short* wqkvT_hi = (unsigned short*)(ws + 29 * MB);  // 4 MB
  unsigned short* wqkvT_lo = (unsigned short*)(ws + 33 * MB);  // 4 MB
  unsigned short* woT_hi = (unsigned short*)(ws + 37 * MB);    // 2 MB
  unsigned short* woT_lo = (unsigned short*)(ws + 39 * MB);    // 2 MB
  unsigned short* h_hi = (unsigned short*)(ws + 41 * MB);      // 4 MB
  unsigned short* h_lo = (unsigned short*)(ws + 45 * MB);      // 4 MB
  unsigned short* q_hi = (unsigned short*)(ws + 49 * MB);      // 4 MB
  unsigned short* q_lo = (unsigned short*)(ws + 53 * MB);      // 4 MB
  unsigned short* k_hi = (unsigned short*)(ws + 57 * MB);      // 2 MB
  unsigned short* k_lo = (unsigned short*)(ws + 59 * MB);      // 2 MB
  unsigned short* vT_hi = (unsigned short*)(ws + 61 * MB);     // 2 MB
  unsigned short* vT_lo = (unsigned short*)(ws + 63 * MB);     // 2 MB
  unsigned short* o_hi = (unsigned short*)(ws + 65 * MB);      // 4 MB
  unsigned short* o_lo = (unsigned short*)(ws + 69 * MB);      // 4 MB
  float* t = (float*)(ws + 73 * MB);                           // 8 MB: 73-81
  float* pm = (float*)(ws + 81 * MB);                          // 0.25 MB
  float* pl = (float*)(ws + 82 * MB);                          // 0.25 MB

  hipMemsetAsync(cnt, 0, 16 * sizeof(int), stream);

  // attention block
  rmsnorm_kernel<0><<<S, 256, 0, stream>>>(x, ln1, nullptr, h_hi, h_lo);
  tconv_kernel<true><<<dim3(16, 16, 1), 256, 0, stream>>>(wq, wqkvT_hi, wqkvT_lo, 1024, 1024, 0, 0);
  tconv_kernel<true><<<dim3(8, 16, 1), 256, 0, stream>>>(wk, wqkvT_hi + (size_t)1024 * 1024,
                                                         wqkvT_lo + (size_t)1024 * 1024, 1024, 512, 0, 0);
  tconv_kernel<true><<<dim3(8, 16, 1), 256, 0, stream>>>(wv, wqkvT_hi + (size_t)1536 * 1024,
                                                         wqkvT_lo + (size_t)1536 * 1024, 1024, 512, 0, 0);
  tconv_kernel<true><<<dim3(16, 16, 1), 256, 0, stream>>>(wo, woT_hi, woT_lo, 1024, 1024, 0, 0);

  gemm_kernel<0><<<dim3(32, 16, 1), 256, 0, stream>>>(h_hi, h_lo, wqkvT_hi, wqkvT_lo, qkv, nullptr,
                                                      nullptr, nullptr, nullptr, nullptr, nullptr,
                                                      nullptr, nullptr, 2048, 1024);
  rope_kernel<<<6144, 256, 0, stream>>>(qkv, sinb, cosb, pos, q_hi, q_lo, k_hi, k_lo);
  vtrans_kernel<<<dim3(32, 8), 256, 0, stream>>>(qkv, vT_hi, vT_lo);
  flash_kernel<<<dim3(32, 16, 2), 256, 0, stream>>>(q_hi, q_lo, k_hi, k_lo, vT_hi, vT_lo, amask,
                                                    po, pm, pl);
  combine_kernel<<<dim3(32, 16), 256, 0, stream>>>(po, pm, pl, o_hi, o_lo);
  gemm_kernel<1><<<dim3(16, 16, 1), 256, 0, stream>>>(o_hi, o_lo, woT_hi, woT_lo, x2, out, nullptr,
                                                      x, nullptr, nullptr, nullptr, nullptr,
                                                      nullptr, 1024, 1024);
  // MoE block
  rmsnorm_kernel<1><<<S, 256, 0, stream>>>(x2, ln2, t, t_bf, nullptr);
  router_kernel<<<S / 4, 256, 0, stream>>>(t, gw, cnt, idxb, wgtb);
  offsets_kernel<<<1, 64, 0, stream>>>(cnt, offs, tmap);

  tconv_kernel<false><<<dim3(32, 16, 8), 256, 0, stream>>>(w1, w1T, nullptr, 1024, 2048,
                                                           (long long)1024 * 2048,
                                                           (long long)2048 * 1024);
  tconv_kernel<false><<<dim3(32, 16, 8), 256, 0, stream>>>(w3, w3T, nullptr, 1024, 2048,
                                                           (long long)1024 * 2048,
                                                           (long long)2048 * 1024);
  gemm_kernel<2><<<dim3(32, 40, 1), 256, 0, stream>>>(t_bf, nullptr, w1T, w3T, nullptr, nullptr, G,
                                                      nullptr, idxb, wgtb, cnt, offs, tmap, 2048,
                                                      1024);
  tconv_kernel<false><<<dim3(16, 32, 8), 256, 0, stream>>>(w2, w2T, nullptr, 2048, 1024,
                                                           (long long)2048 * 1024,
                                                           (long long)1024 * 2048);
  gemm_kernel<3><<<dim3(16, 40, 1), 256, 0, stream>>>(G, nullptr, w2T, nullptr, out, nullptr,
                                                      nullptr, nullptr, idxb, wgtb, cnt, offs, tmap,
                                                      1024, 2048);
}

// Round 8
// 389.734 us; speedup vs baseline: 1.0117x; 1.0117x over previous
//
#include <hip/hip_runtime.h>

#define S 2048
#define H 1024
#define NH 16
#define NKV 8
#define HD 64
#define NE 8
#define ID 2048

typedef short bf16x8 __attribute__((ext_vector_type(8)));
typedef short bf16x4 __attribute__((ext_vector_type(4)));
typedef float f32x4 __attribute__((ext_vector_type(4)));

__device__ __forceinline__ unsigned short f2bf(float f) {
  unsigned u = __builtin_bit_cast(unsigned, f);
  u += 0x7FFFu + ((u >> 16) & 1u);
  return (unsigned short)(u >> 16);
}
__device__ __forceinline__ float bf2f(unsigned short h) {
  unsigned u = ((unsigned)h) << 16;
  return __builtin_bit_cast(float, u);
}

typedef const __attribute__((address_space(1))) unsigned int gas_u32;
typedef __attribute__((address_space(3))) unsigned int las_u32;
// direct global->LDS DMA, 16B per lane; LDS dest = wave-uniform base + lane*16
__device__ __forceinline__ void gload16(const unsigned short* g, unsigned short* l) {
  __builtin_amdgcn_global_load_lds((gas_u32*)g, (las_u32*)l, 16, 0, 0);
}

// ---------------- RMSNorm ----------------
// OUTM 0: write hi+lo bf16 planes. OUTM 1: write f32 + hi bf16.
template <int OUTM>
__global__ __launch_bounds__(256) void rmsnorm_kernel(const float* __restrict__ x,
                                                      const float* __restrict__ wgt,
                                                      float* __restrict__ outf,
                                                      unsigned short* __restrict__ ohi,
                                                      unsigned short* __restrict__ olo) {
  int row = blockIdx.x;
  const float* xr = x + (size_t)row * H;
  int tid = threadIdx.x;
  float v[4];
  float ss = 0.f;
#pragma unroll
  for (int i = 0; i < 4; i++) {
    v[i] = xr[tid + i * 256];
    ss += v[i] * v[i];
  }
#pragma unroll
  for (int off = 1; off < 64; off <<= 1) ss += __shfl_xor(ss, off);
  __shared__ float part[4];
  if ((tid & 63) == 0) part[tid >> 6] = ss;
  __syncthreads();
  float tot = part[0] + part[1] + part[2] + part[3];
  float r = rsqrtf(tot * (1.f / H) + 1e-6f);
#pragma unroll
  for (int i = 0; i < 4; i++) {
    int c = tid + i * 256;
    float vv = v[i] * r * wgt[c];
    size_t o = (size_t)row * H + c;
    if (OUTM == 0) {
      unsigned short h_ = f2bf(vv);
      ohi[o] = h_;
      olo[o] = f2bf(vv - bf2f(h_));
    } else {
      outf[o] = vv;
      ohi[o] = f2bf(vv);
    }
  }
}

// ---------------- transpose-convert: src f32 [K][N] -> dst bf16 [N][K] ----------------
template <bool LO>
__global__ __launch_bounds__(256) void tconv_kernel(const float* __restrict__ src,
                                                    unsigned short* __restrict__ hi,
                                                    unsigned short* __restrict__ lo,
                                                    int K, int N, long long sStride,
                                                    long long dStride) {
  int nt = blockIdx.x, kt = blockIdx.y, b = blockIdx.z;
  src += (size_t)b * sStride;
  hi += (size_t)b * dStride;
  if (LO) lo += (size_t)b * dStride;
  __shared__ float tile[64][65];
  int tid = threadIdx.x;
  int r = tid >> 2, cs = (tid & 3) * 16;
  const float* s0 = src + (size_t)(kt * 64 + r) * N + nt * 64 + cs;
#pragma unroll
  for (int i = 0; i < 16; i += 4) {
    float4 a = *(const float4*)(s0 + i);
    tile[r][cs + i] = a.x;
    tile[r][cs + i + 1] = a.y;
    tile[r][cs + i + 2] = a.z;
    tile[r][cs + i + 3] = a.w;
  }
  __syncthreads();
  int n = nt * 64 + r;
  size_t dbase = (size_t)n * K + kt * 64 + cs;
  unsigned short th[16], tl[16];
#pragma unroll
  for (int i = 0; i < 16; i++) {
    float vv = tile[cs + i][r];
    unsigned short h_ = f2bf(vv);
    th[i] = h_;
    if (LO) tl[i] = f2bf(vv - bf2f(h_));
  }
  *(bf16x8*)(hi + dbase) = *(bf16x8*)&th[0];
  *(bf16x8*)(hi + dbase + 8) = *(bf16x8*)&th[8];
  if (LO) {
    *(bf16x8*)(lo + dbase) = *(bf16x8*)&tl[0];
    *(bf16x8*)(lo + dbase + 8) = *(bf16x8*)&tl[8];
  }
}

// ---------------- MFMA GEMM, 128x64 tile, BK=64, gload_lds + XOR swizzle ----------------
// MODE 0: QKV   A=h hi/lo [M][K], B=wqkvT hi/lo [N][K], 3-term split, C=qkv f32
// MODE 1: OPROJ same + resid, dual store (x2 and out)
// MODE 2: MOEA  A=t_bf gathered (tile table grid), Bh=w1T Bl=w3T, silu(g1)*g3 -> G bf16
// MODE 3: MOEB  A=G (tile table grid), B=w2T, atomicAdd out += v*wgt
template <int MODE>
__global__ __launch_bounds__(256) void gemm_kernel(
    const unsigned short* __restrict__ Ah, const unsigned short* __restrict__ Al,
    const unsigned short* __restrict__ Bh, const unsigned short* __restrict__ Bl,
    float* __restrict__ C, float* __restrict__ C2, unsigned short* __restrict__ Gout,
    const float* __restrict__ resid, const int* __restrict__ idx,
    const float* __restrict__ wgt, const int* __restrict__ cnt,
    const int* __restrict__ offs, const int* __restrict__ tmap, int N, int K) {
  int n0 = blockIdx.x * 64, m0, e = 0;
  int ce = 0, gbase = 0;
  if (MODE >= 2) {
    int ntiles = tmap[63];
    if ((int)blockIdx.y >= ntiles) return;
    int packed = tmap[blockIdx.y];
    e = packed >> 16;
    m0 = (packed & 0xffff) * 128;
    ce = cnt[e];
    gbase = offs[e];
  } else {
    m0 = blockIdx.y * 128;
  }
  const unsigned short* bhp = Bh;
  const unsigned short* blp = Bl;
  if (MODE == 2) {
    bhp += (size_t)e * 2048 * 1024;
    blp += (size_t)e * 2048 * 1024;
  }
  if (MODE == 3) bhp += (size_t)e * 1024 * 2048;

  __shared__ __align__(16) unsigned short tAh[128 * 64];
  __shared__ __align__(16) unsigned short tAl[128 * 64];
  __shared__ __align__(16) unsigned short tBh[64 * 64];
  __shared__ __align__(16) unsigned short tBl[64 * 64];

  int tid = threadIdx.x, w = tid >> 6, lane = tid & 63;
  int lr = lane & 15, g = lane >> 4;
  int rloc = lane >> 3, slotg = (lane & 7) ^ rloc;
  int wm = w >> 1, wn = w & 1;

  // per-chunk per-lane source element offsets (k0=0); inverse-swizzled slot
  unsigned aOff[4], bOff[2];
#pragma unroll
  for (int cc = 0; cc < 4; cc++) {
    int rr = w * 32 + cc * 8 + rloc;  // tile-local row 0..127
    if (MODE == 2) {
      int gr = m0 + rr;
      if (gr > ce - 1) gr = ce - 1;
      int tok = idx[e * S + gr];
      aOff[cc] = (unsigned)(tok * K + slotg * 8);
    } else if (MODE == 3) {
      int gr = gbase + m0 + rr;
      if (gr > 4095) gr = 4095;
      aOff[cc] = (unsigned)(gr * K + slotg * 8);
    } else {
      aOff[cc] = (unsigned)((m0 + rr) * K + slotg * 8);
    }
  }
#pragma unroll
  for (int cc = 0; cc < 2; cc++) {
    int rr = w * 16 + cc * 8 + rloc;  // tile-local n-row 0..63
    bOff[cc] = (unsigned)((n0 + rr) * K + slotg * 8);
  }

  f32x4 acc[4][2], acc2[4][2];
#pragma unroll
  for (int i = 0; i < 4; i++)
#pragma unroll
    for (int j = 0; j < 2; j++) {
      acc[i][j] = f32x4{0.f, 0.f, 0.f, 0.f};
      if (MODE == 2) acc2[i][j] = f32x4{0.f, 0.f, 0.f, 0.f};
    }

  for (int k0 = 0; k0 < K; k0 += 64) {
    __syncthreads();
#pragma unroll
    for (int cc = 0; cc < 4; cc++) {
      int cb = (w * 4 + cc) * 512;
      gload16(Ah + aOff[cc] + k0, &tAh[cb]);
      if (MODE <= 1) gload16(Al + aOff[cc] + k0, &tAl[cb]);
    }
#pragma unroll
    for (int cc = 0; cc < 2; cc++) {
      int cb = (w * 2 + cc) * 512;
      gload16(bhp + bOff[cc] + k0, &tBh[cb]);
      if (MODE <= 2) gload16(blp + bOff[cc] + k0, &tBl[cb]);
    }
    __syncthreads();
    bf16x8 fah[4][2], fal[4][2];
#pragma unroll
    for (int i = 0; i < 4; i++) {
      int ar = wm * 64 + i * 16 + lr;
#pragma unroll
      for (int kk = 0; kk < 2; kk++) {
        int off = ar * 64 + (((kk * 4 + g) ^ (ar & 7)) * 8);
        fah[i][kk] = *(const bf16x8*)&tAh[off];
        if (MODE <= 1) fal[i][kk] = *(const bf16x8*)&tAl[off];
      }
    }
#pragma unroll
    for (int j = 0; j < 2; j++) {
      int br = wn * 32 + j * 16 + lr;
      bf16x8 fbh[2], fbl[2];
#pragma unroll
      for (int kk = 0; kk < 2; kk++) {
        int off = br * 64 + (((kk * 4 + g) ^ (br & 7)) * 8);
        fbh[kk] = *(const bf16x8*)&tBh[off];
        if (MODE <= 2) fbl[kk] = *(const bf16x8*)&tBl[off];
      }
#pragma unroll
      for (int i = 0; i < 4; i++) {
#pragma unroll
        for (int kk = 0; kk < 2; kk++) {
          acc[i][j] = __builtin_amdgcn_mfma_f32_16x16x32_bf16(fah[i][kk], fbh[kk], acc[i][j], 0, 0, 0);
          if (MODE <= 1) {
            acc[i][j] = __builtin_amdgcn_mfma_f32_16x16x32_bf16(fah[i][kk], fbl[kk], acc[i][j], 0, 0, 0);
            acc[i][j] = __builtin_amdgcn_mfma_f32_16x16x32_bf16(fal[i][kk], fbh[kk], acc[i][j], 0, 0, 0);
          }
          if (MODE == 2)
            acc2[i][j] = __builtin_amdgcn_mfma_f32_16x16x32_bf16(fah[i][kk], fbl[kk], acc2[i][j], 0, 0, 0);
        }
      }
    }
  }
  // epilogue
#pragma unroll
  for (int i = 0; i < 4; i++)
#pragma unroll
    for (int j = 0; j < 2; j++)
#pragma unroll
      for (int r = 0; r < 4; r++) {
        int grow = wm * 64 + i * 16 + g * 4 + r;
        int gcol = n0 + wn * 32 + j * 16 + lr;
        float v = acc[i][j][r];
        if (MODE == 0) {
          C[(size_t)(m0 + grow) * N + gcol] = v;
        } else if (MODE == 1) {
          float o = v + resid[(size_t)(m0 + grow) * N + gcol];
          C[(size_t)(m0 + grow) * N + gcol] = o;
          C2[(size_t)(m0 + grow) * N + gcol] = o;
        } else if (MODE == 2) {
          if (m0 + grow < ce) {
            float g3 = acc2[i][j][r];
            float sg = v / (1.f + __expf(-v));
            Gout[(size_t)(gbase + m0 + grow) * 2048 + gcol] = f2bf(sg * g3);
          }
        } else {
          if (m0 + grow < ce) {
            int tok = idx[e * S + m0 + grow];
            float wv = wgt[e * S + m0 + grow];
            atomicAdd(&C[(size_t)tok * 1024 + gcol], v * wv);
          }
        }
      }
}

// ---------------- RoPE: qkv f32 -> q hi/lo (x0.125), k hi/lo planes ----------------
__global__ __launch_bounds__(256) void rope_kernel(
    const float* __restrict__ qkv, const float* __restrict__ sinb,
    const float* __restrict__ cosb, const int* __restrict__ pos,
    unsigned short* __restrict__ qhi, unsigned short* __restrict__ qlo,
    unsigned short* __restrict__ khi, unsigned short* __restrict__ klo) {
  int i = blockIdx.x * 256 + threadIdx.x;
  int d = i & 31;
  int s = (i >> 5) & 2047;
  int hh = i >> 16;  // 0..23
  int p = pos[s];
  float c0 = cosb[p * HD + d], c1 = cosb[p * HD + d + 32];
  float s0 = sinb[p * HD + d], s1 = sinb[p * HD + d + 32];
  const float* srcb = qkv + (size_t)s * 2048;
  if (hh < NH) {
    float x0 = srcb[hh * HD + d], x1 = srcb[hh * HD + d + 32];
    float r0 = (x0 * c0 - x1 * s0) * 0.125f;
    float r1 = (x1 * c1 + x0 * s1) * 0.125f;
    size_t o = ((size_t)hh * S + s) * HD + d;
    unsigned short h0 = f2bf(r0), h1 = f2bf(r1);
    qhi[o] = h0;
    qlo[o] = f2bf(r0 - bf2f(h0));
    qhi[o + 32] = h1;
    qlo[o + 32] = f2bf(r1 - bf2f(h1));
  } else {
    int hk = hh - NH;
    float x0 = srcb[1024 + hk * HD + d], x1 = srcb[1024 + hk * HD + d + 32];
    float r0 = x0 * c0 - x1 * s0;
    float r1 = x1 * c1 + x0 * s1;
    size_t o = ((size_t)hk * S + s) * HD + d;
    unsigned short h0 = f2bf(r0), h1 = f2bf(r1);
    khi[o] = h0;
    klo[o] = f2bf(r0 - bf2f(h0));
    khi[o + 32] = h1;
    klo[o + 32] = f2bf(r1 - bf2f(h1));
  }
}

// ---------------- V transpose: qkv v-cols -> vT[hk][d][s] hi/lo bf16 ----------------
__global__ __launch_bounds__(256) void vtrans_kernel(const float* __restrict__ qkv,
                                                     unsigned short* __restrict__ vThi,
                                                     unsigned short* __restrict__ vTlo) {
  int st = blockIdx.x, hk = blockIdx.y;
  __shared__ float tile[64][65];
  int tid = threadIdx.x;
  int r = tid >> 2, seg = (tid & 3) * 16;
  const float* src = qkv + (size_t)(st * 64 + r) * 2048 + 1536 + hk * HD + seg;
#pragma unroll
  for (int i = 0; i < 16; i += 4) {
    float4 a = *(const float4*)(src + i);
    tile[r][seg + i] = a.x;
    tile[r][seg + i + 1] = a.y;
    tile[r][seg + i + 2] = a.z;
    tile[r][seg + i + 3] = a.w;
  }
  __syncthreads();
  int d = tid >> 2, ss = (tid & 3) * 16;
  unsigned short th[16], tl[16];
#pragma unroll
  for (int i = 0; i < 16; i++) {
    float vv = tile[ss + i][d];
    unsigned short h_ = f2bf(vv);
    th[i] = h_;
    tl[i] = f2bf(vv - bf2f(h_));
  }
  size_t dst = ((size_t)hk * HD + d) * S + st * 64 + ss;
  *(bf16x8*)(vThi + dst) = *(bf16x8*)&th[0];
  *(bf16x8*)(vThi + dst + 8) = *(bf16x8*)&th[8];
  *(bf16x8*)(vTlo + dst) = *(bf16x8*)&tl[0];
  *(bf16x8*)(vTlo + dst + 8) = *(bf16x8*)&tl[8];
}

// ---------------- flash attention (MFMA, double-buffered 2-phase pipeline) ----------------
// grid (32 qt, 16 heads, 2 kv-splits). LDS 80KB (2x K/V dbuf + P hi/lo) -> 2 blocks/CU.
// Per iter: issue stage(t+1) -> compute(t) -> barrier (vmcnt drain lands after compute).
#define FSWZ(row, byteoff) ((byteoff) ^ (((row) & 7) << 4))

__global__ __launch_bounds__(256) void flash_kernel(
    const unsigned short* __restrict__ qhi, const unsigned short* __restrict__ qlo,
    const unsigned short* __restrict__ khip, const unsigned short* __restrict__ klop,
    const unsigned short* __restrict__ vthip, const unsigned short* __restrict__ vtlop,
    const float* __restrict__ amask, float* __restrict__ po, float* __restrict__ pm,
    float* __restrict__ pl) {
  int qt = (int)gridDim.x - 1 - (int)blockIdx.x;  // long blocks first
  int head = blockIdx.y, z = blockIdx.z;
  int tid = threadIdx.x;
  int w = tid >> 6, lane = tid & 63;
  int lr = lane & 15, g = lane >> 4;
  int rloc = lane >> 3, slotg = (lane & 7) ^ rloc;

  __shared__ __align__(16) unsigned short Khi[2][64 * 64];
  __shared__ __align__(16) unsigned short Klo[2][64 * 64];
  __shared__ __align__(16) unsigned short Vhi[2][64 * 64];
  __shared__ __align__(16) unsigned short Vlo[2][64 * 64];
  __shared__ __align__(16) unsigned short Phi[4][16 * 64];
  __shared__ __align__(16) unsigned short Plo[4][16 * 64];

  int qrow = qt * 64 + w * 16 + lr;
  bf16x8 qh[2], ql[2];
  {
    const unsigned short* qb = qhi + ((size_t)head * S + qrow) * HD;
    const unsigned short* qb2 = qlo + ((size_t)head * S + qrow) * HD;
    qh[0] = *(const bf16x8*)(qb + g * 8);
    qh[1] = *(const bf16x8*)(qb + 32 + g * 8);
    ql[0] = *(const bf16x8*)(qb2 + g * 8);
    ql[1] = *(const bf16x8*)(qb2 + 32 + g * 8);
  }

  f32x4 oacc[4];
#pragma unroll
  for (int dg = 0; dg < 4; dg++) oacc[dg] = f32x4{0.f, 0.f, 0.f, 0.f};
  float m = -1e30f, l = 0.f;

  const unsigned short* kbh = khip + (size_t)(head >> 1) * S * HD;
  const unsigned short* kbl = klop + (size_t)(head >> 1) * S * HD;
  const unsigned short* vbh = vthip + (size_t)(head >> 1) * HD * S;
  const unsigned short* vbl = vtlop + (size_t)(head >> 1) * HD * S;
  char* pbase = (char*)Phi[w];
  char* plbase = (char*)Plo[w];

  int nblk = qt + 1;
  int b0 = (z * nblk) >> 1, b1 = ((z + 1) * nblk) >> 1;

  // stage chunk indices (wave-uniform LDS base, per-lane global source)
  int sc = w * 2, sr0 = sc * 8 + rloc, sr1 = sr0 + 8;

  if (b0 < b1) {
    // prologue: stage first tile into buf 0
    int kv0 = b0 * 64;
    gload16(kbh + (size_t)(kv0 + sr0) * HD + slotg * 8, &Khi[0][sc * 512]);
    gload16(kbh + (size_t)(kv0 + sr1) * HD + slotg * 8, &Khi[0][(sc + 1) * 512]);
    gload16(kbl + (size_t)(kv0 + sr0) * HD + slotg * 8, &Klo[0][sc * 512]);
    gload16(kbl + (size_t)(kv0 + sr1) * HD + slotg * 8, &Klo[0][(sc + 1) * 512]);
    gload16(vbh + (size_t)sr0 * S + kv0 + slotg * 8, &Vhi[0][sc * 512]);
    gload16(vbh + (size_t)sr1 * S + kv0 + slotg * 8, &Vhi[0][(sc + 1) * 512]);
    gload16(vbl + (size_t)sr0 * S + kv0 + slotg * 8, &Vlo[0][sc * 512]);
    gload16(vbl + (size_t)sr1 * S + kv0 + slotg * 8, &Vlo[0][(sc + 1) * 512]);
  }
  float am = (b0 < b1) ? amask[b0 * 64 + lane] : 0.f;
  __syncthreads();  // drains vmcnt: buf 0 ready

  for (int kb = b0; kb < b1; kb++) {
    int buf = (kb - b0) & 1;
    // issue next-tile stage into the other buffer (hidden under this tile's compute)
    float am_next = 0.f;
    if (kb + 1 < b1) {
      int kv1 = (kb + 1) * 64;
      int nb = buf ^ 1;
      gload16(kbh + (size_t)(kv1 + sr0) * HD + slotg * 8, &Khi[nb][sc * 512]);
      gload16(kbh + (size_t)(kv1 + sr1) * HD + slotg * 8, &Khi[nb][(sc + 1) * 512]);
      gload16(kbl + (size_t)(kv1 + sr0) * HD + slotg * 8, &Klo[nb][sc * 512]);
      gload16(kbl + (size_t)(kv1 + sr1) * HD + slotg * 8, &Klo[nb][(sc + 1) * 512]);
      gload16(vbh + (size_t)sr0 * S + kv1 + slotg * 8, &Vhi[nb][sc * 512]);
      gload16(vbh + (size_t)sr1 * S + kv1 + slotg * 8, &Vhi[nb][(sc + 1) * 512]);
      gload16(vbl + (size_t)sr0 * S + kv1 + slotg * 8, &Vlo[nb][sc * 512]);
      gload16(vbl + (size_t)sr1 * S + kv1 + slotg * 8, &Vlo[nb][(sc + 1) * 512]);
      am_next = amask[kv1 + lane];
    }
    unsigned long long vm = __ballot(am > 0.f);
    const char* khb = (const char*)Khi[buf];
    const char* klb = (const char*)Klo[buf];
    const char* vhb = (const char*)Vhi[buf];
    const char* vlb = (const char*)Vlo[buf];

    // ---- QK^T (S^T): lane -> q-row lr, kv = c*16 + 4*g + r ----
    f32x4 sacc[4];
#pragma unroll
    for (int c = 0; c < 4; c++) sacc[c] = f32x4{0.f, 0.f, 0.f, 0.f};
#pragma unroll
    for (int c = 0; c < 4; c++) {
#pragma unroll
      for (int kc = 0; kc < 2; kc++) {
        int row = c * 16 + lr;
        int bo = FSWZ(row, row * 128 + kc * 64 + g * 16);
        bf16x8 khf = *(const bf16x8*)(khb + bo);
        bf16x8 klf = *(const bf16x8*)(klb + bo);
        sacc[c] = __builtin_amdgcn_mfma_f32_16x16x32_bf16(khf, qh[kc], sacc[c], 0, 0, 0);
        sacc[c] = __builtin_amdgcn_mfma_f32_16x16x32_bf16(khf, ql[kc], sacc[c], 0, 0, 0);
        sacc[c] = __builtin_amdgcn_mfma_f32_16x16x32_bf16(klf, qh[kc], sacc[c], 0, 0, 0);
      }
    }
    // ---- mask + online softmax ----
    int qloc = w * 16 + lr;
    bool diag = (kb == qt);
    float tm = -1e30f;
#pragma unroll
    for (int c = 0; c < 4; c++) {
#pragma unroll
      for (int r = 0; r < 4; r++) {
        int kvloc = c * 16 + 4 * g + r;
        bool vis = ((vm >> kvloc) & 1ull) && (!diag || kvloc <= qloc);
        float sv = vis ? sacc[c][r] : -1e30f;
        sacc[c][r] = sv;
        tm = fmaxf(tm, sv);
      }
    }
    tm = fmaxf(tm, __shfl_xor(tm, 16));
    tm = fmaxf(tm, __shfl_xor(tm, 32));
    float newm = fmaxf(m, tm);
    float alpha = __expf(m - newm);
    float rs = 0.f;
#pragma unroll
    for (int c = 0; c < 4; c++) {
#pragma unroll
      for (int r = 0; r < 4; r++) {
        float p = __expf(sacc[c][r] - newm);
        sacc[c][r] = p;
        rs += p;
      }
    }
    rs += __shfl_xor(rs, 16);
    rs += __shfl_xor(rs, 32);
    m = newm;
    l = l * alpha + rs;
#pragma unroll
    for (int dg = 0; dg < 4; dg++) {
#pragma unroll
      for (int r = 0; r < 4; r++) oacc[dg][r] *= alpha;
    }
    // ---- write P hi/lo to per-wave LDS ----
#pragma unroll
    for (int c = 0; c < 4; c++) {
      bf16x4 ph, pl2;
#pragma unroll
      for (int r = 0; r < 4; r++) {
        float pv = sacc[c][r];
        unsigned short h_ = f2bf(pv);
        ph[r] = (short)h_;
        pl2[r] = (short)f2bf(pv - bf2f(h_));
      }
      int bo = FSWZ(lr, lr * 128 + (c * 16 + 4 * g) * 2);
      *(bf16x4*)(pbase + bo) = ph;
      *(bf16x4*)(plbase + bo) = pl2;
    }
    bf16x8 pbh[2], pbl[2];
#pragma unroll
    for (int kc = 0; kc < 2; kc++) {
      int bo = FSWZ(lr, lr * 128 + kc * 64 + g * 16);
      pbh[kc] = *(const bf16x8*)(pbase + bo);
      pbl[kc] = *(const bf16x8*)(plbase + bo);
    }
    // ---- PV: O^T += V^T * P^T ----
#pragma unroll
    for (int dg = 0; dg < 4; dg++) {
#pragma unroll
      for (int kc = 0; kc < 2; kc++) {
        int row = dg * 16 + lr;
        int bo = FSWZ(row, row * 128 + kc * 64 + g * 16);
        bf16x8 vhf = *(const bf16x8*)(vhb + bo);
        bf16x8 vlf = *(const bf16x8*)(vlb + bo);
        oacc[dg] = __builtin_amdgcn_mfma_f32_16x16x32_bf16(vhf, pbh[kc], oacc[dg], 0, 0, 0);
        oacc[dg] = __builtin_amdgcn_mfma_f32_16x16x32_bf16(vhf, pbl[kc], oacc[dg], 0, 0, 0);
        oacc[dg] = __builtin_amdgcn_mfma_f32_16x16x32_bf16(vlf, pbh[kc], oacc[dg], 0, 0, 0);
      }
    }
    am = am_next;
    __syncthreads();  // drains next-tile stage (hidden under compute) + protects buf reuse
  }

  // write unnormalized f32 partials
  size_t pb = (size_t)(qt * 16 + head) * 2 + z;
  int row = w * 16 + lr;
  if (g == 0) {
    pm[pb * 64 + row] = m;
    pl[pb * 64 + row] = l;
  }
  float* pob = po + pb * 4096 + (size_t)row * 64;
#pragma unroll
  for (int dg = 0; dg < 4; dg++) {
    float4 v4 = {oacc[dg][0], oacc[dg][1], oacc[dg][2], oacc[dg][3]};
    *(float4*)(pob + dg * 16 + 4 * g) = v4;
  }
}

// merge 2 kv-split partials -> o hi/lo bf16 planes
__global__ __launch_bounds__(256) void combine_kernel(const float* __restrict__ po,
                                                      const float* __restrict__ pm,
                                                      const float* __restrict__ pl,
                                                      unsigned short* __restrict__ ohi,
                                                      unsigned short* __restrict__ olo) {
  int qt = blockIdx.x, head = blockIdx.y;
  int r = threadIdx.x >> 2, dg = (threadIdx.x & 3) * 16;
  size_t base = (size_t)(qt * 16 + head) * 2;
  float m0v = pm[base * 64 + r], m1v = pm[(base + 1) * 64 + r];
  float l0 = pl[base * 64 + r], l1 = pl[(base + 1) * 64 + r];
  float M = fmaxf(m0v, m1v);
  float w0 = __expf(m0v - M), w1 = __expf(m1v - M);
  float inv = 1.f / (w0 * l0 + w1 * l1);
  const float* p0 = po + base * 4096 + (size_t)r * 64 + dg;
  const float* p1 = po + (base + 1) * 4096 + (size_t)r * 64 + dg;
  unsigned short th[16], tl[16];
#pragma unroll
  for (int i = 0; i < 16; i += 4) {
    float4 a = *(const float4*)(p0 + i);
    float4 b = *(const float4*)(p1 + i);
    float vv[4] = {(w0 * a.x + w1 * b.x) * inv, (w0 * a.y + w1 * b.y) * inv,
                   (w0 * a.z + w1 * b.z) * inv, (w0 * a.w + w1 * b.w) * inv};
#pragma unroll
    for (int j = 0; j < 4; j++) {
      unsigned short h_ = f2bf(vv[j]);
      th[i + j] = h_;
      tl[i + j] = f2bf(vv[j] - bf2f(h_));
    }
  }
  size_t ob = (size_t)(qt * 64 + r) * 1024 + head * 64 + dg;
  *(bf16x8*)(ohi + ob) = *(bf16x8*)&th[0];
  *(bf16x8*)(ohi + ob + 8) = *(bf16x8*)&th[8];
  *(bf16x8*)(olo + ob) = *(bf16x8*)&tl[0];
  *(bf16x8*)(olo + ob + 8) = *(bf16x8*)&tl[8];
}

// ---------------- router ----------------
__global__ __launch_bounds__(256) void router_kernel(const float* __restrict__ t,
                                                     const float* __restrict__ gw,
                                                     int* __restrict__ cnt,
                                                     int* __restrict__ idxb,
                                                     float* __restrict__ wgtb) {
  int tok = blockIdx.x * 4 + (threadIdx.x >> 6);
  int lane = threadIdx.x & 63;
  const float* tr = t + (size_t)tok * H;
  float acc[NE];
#pragma unroll
  for (int e = 0; e < NE; e++) acc[e] = 0.f;
#pragma unroll
  for (int i = 0; i < 16; i++) {
    float tv = tr[lane * 16 + i];
    const float* g = gw + (size_t)(lane * 16 + i) * NE;
#pragma unroll
    for (int e = 0; e < NE; e++) acc[e] += tv * g[e];
  }
#pragma unroll
  for (int off = 1; off < 64; off <<= 1) {
#pragma unroll
    for (int e = 0; e < NE; e++) acc[e] += __shfl_xor(acc[e], off);
  }
  if (lane == 0) {
    int e1 = 0;
#pragma unroll
    for (int e = 1; e < NE; e++)
      if (acc[e] > acc[e1]) e1 = e;
    int e2 = -1;
#pragma unroll
    for (int e = 0; e < NE; e++)
      if (e != e1 && (e2 < 0 || acc[e] > acc[e2])) e2 = e;
    float w1v = 1.f / (1.f + __expf(acc[e2] - acc[e1]));
    float w2v = 1.f - w1v;
    int p1 = atomicAdd(&cnt[e1], 1);
    idxb[e1 * S + p1] = tok;
    wgtb[e1 * S + p1] = w1v;
    int p2 = atomicAdd(&cnt[e2], 1);
    idxb[e2 * S + p2] = tok;
    wgtb[e2 * S + p2] = w2v;
  }
}

// prefix offsets + dense tile table: tmap[t] = (expert<<16) | m_tile, tmap[63] = count
__global__ void offsets_kernel(const int* __restrict__ cnt, int* __restrict__ offs,
                               int* __restrict__ tmap) {
  if (threadIdx.x == 0 && blockIdx.x == 0) {
    int a = 0, t = 0;
    for (int e = 0; e < NE; e++) {
      offs[e] = a;
      a += cnt[e];
      int nt = (cnt[e] + 127) >> 7;
      for (int i = 0; i < nt; i++) tmap[t++] = (e << 16) | i;
    }
    offs[NE] = a;
    tmap[63] = t;  // t <= 40
  }
}

// ---------------- launch ----------------
extern "C" void kernel_launch(void* const* d_in, const int* in_sizes, int n_in,
                              void* d_out, int out_size, void* d_ws, size_t ws_size,
                              hipStream_t stream) {
  const float* x = (const float*)d_in[0];
  const float* amask = (const float*)d_in[1];
  const int* pos = (const int*)d_in[2];
  const float* sinb = (const float*)d_in[3];
  const float* cosb = (const float*)d_in[4];
  const float* wq = (const float*)d_in[5];
  const float* wk = (const float*)d_in[6];
  const float* wv = (const float*)d_in[7];
  const float* wo = (const float*)d_in[8];
  const float* ln1 = (const float*)d_in[9];
  const float* ln2 = (const float*)d_in[10];
  const float* gw = (const float*)d_in[11];
  const float* w1 = (const float*)d_in[12];
  const float* w3 = (const float*)d_in[13];
  const float* w2 = (const float*)d_in[14];
  float* out = (float*)d_out;

  char* ws = (char*)d_ws;
  const size_t MB = 1024 * 1024;
  // persistent
  float* x2 = (float*)(ws + 0 * MB);                    // 8 MB
  unsigned short* t_bf = (unsigned short*)(ws + 8 * MB);  // 4 MB
  int* cnt = (int*)(ws + 12 * MB);
  int* offs = cnt + 16;
  int* tmap = cnt + 32;            // 64 ints
  int* idxb = cnt + 128;
  float* wgtb = (float*)(idxb + NE * S);
  // MoE region
  unsigned short* G = (unsigned short*)(ws + 13 * MB);    // 16 MB: 13-29
  unsigned short* w1T = (unsigned short*)(ws + 29 * MB);  // 32 MB: 29-61
  unsigned short* w3T = (unsigned short*)(ws + 61 * MB);  // 32 MB: 61-93
  unsigned short* w2T = (unsigned short*)(ws + 29 * MB);  // reuse after mode2
  // phase-1 overlays (dead before MoE tconvs run)
  float* qkv = (float*)(ws + 13 * MB);                       // 16 MB: 13-29 (dead by flash)
  float* po = (float*)(ws + 13 * MB);                        // 16 MB: flash partials (dead by mode2)
  unsigned short* wqkvT_hi = (unsigned short*)(ws + 29 * MB);  // 4 MB
  unsigned short* wqkvT_lo = (unsigned short*)(ws + 33 * MB);  // 4 MB
  unsigned short* woT_hi = (unsigned short*)(ws + 37 * MB);    // 2 MB
  unsigned short* woT_lo = (unsigned short*)(ws + 39 * MB);    // 2 MB
  unsigned short* h_hi = (unsigned short*)(ws + 41 * MB);      // 4 MB
  unsigned short* h_lo = (unsigned short*)(ws + 45 * MB);      // 4 MB
  unsigned short* q_hi = (unsigned short*)(ws + 49 * MB);      // 4 MB
  unsigned short* q_lo = (unsigned short*)(ws + 53 * MB);      // 4 MB
  unsigned short* k_hi = (unsigned short*)(ws + 57 * MB);      // 2 MB
  unsigned short* k_lo = (unsigned short*)(ws + 59 * MB);      // 2 MB
  unsigned short* vT_hi = (unsigned short*)(ws + 61 * MB);     // 2 MB
  unsigned short* vT_lo = (unsigned short*)(ws + 63 * MB);     // 2 MB
  unsigned short* o_hi = (unsigned short*)(ws + 65 * MB);      // 4 MB
  unsigned short* o_lo = (unsigned short*)(ws + 69 * MB);      // 4 MB
  float* t = (float*)(ws + 73 * MB);                           // 8 MB: 73-81
  float* pm = (float*)(ws + 81 * MB);                          // 0.25 MB
  float* pl = (float*)(ws + 82 * MB);                          // 0.25 MB

  hipMemsetAsync(cnt, 0, 16 * sizeof(int), stream);

  // attention block
  rmsnorm_kernel<0><<<S, 256, 0, stream>>>(x, ln1, nullptr, h_hi, h_lo);
  tconv_kernel<true><<<dim3(16, 16, 1), 256, 0, stream>>>(wq, wqkvT_hi, wqkvT_lo, 1024, 1024, 0, 0);
  tconv_kernel<true><<<dim3(8, 16, 1), 256, 0, stream>>>(wk, wqkvT_hi + (size_t)1024 * 1024,
                                                         wqkvT_lo + (size_t)1024 * 1024, 1024, 512, 0, 0);
  tconv_kernel<true><<<dim3(8, 16, 1), 256, 0, stream>>>(wv, wqkvT_hi + (size_t)1536 * 1024,
                                                         wqkvT_lo + (size_t)1536 * 1024, 1024, 512, 0, 0);
  tconv_kernel<true><<<dim3(16, 16, 1), 256, 0, stream>>>(wo, woT_hi, woT_lo, 1024, 1024, 0, 0);

  gemm_kernel<0><<<dim3(32, 16, 1), 256, 0, stream>>>(h_hi, h_lo, wqkvT_hi, wqkvT_lo, qkv, nullptr,
                                                      nullptr, nullptr, nullptr, nullptr, nullptr,
                                                      nullptr, nullptr, 2048, 1024);
  rope_kernel<<<6144, 256, 0, stream>>>(qkv, sinb, cosb, pos, q_hi, q_lo, k_hi, k_lo);
  vtrans_kernel<<<dim3(32, 8), 256, 0, stream>>>(qkv, vT_hi, vT_lo);
  flash_kernel<<<dim3(32, 16, 2), 256, 0, stream>>>(q_hi, q_lo, k_hi, k_lo, vT_hi, vT_lo, amask,
                                                    po, pm, pl);
  combine_kernel<<<dim3(32, 16), 256, 0, stream>>>(po, pm, pl, o_hi, o_lo);
  gemm_kernel<1><<<dim3(16, 16, 1), 256, 0, stream>>>(o_hi, o_lo, woT_hi, woT_lo, x2, out, nullptr,
                                                      x, nullptr, nullptr, nullptr, nullptr,
                                                      nullptr, 1024, 1024);
  // MoE block
  rmsnorm_kernel<1><<<S, 256, 0, stream>>>(x2, ln2, t, t_bf, nullptr);
  router_kernel<<<S / 4, 256, 0, stream>>>(t, gw, cnt, idxb, wgtb);
  offsets_kernel<<<1, 64, 0, stream>>>(cnt, offs, tmap);

  tconv_kernel<false><<<dim3(32, 16, 8), 256, 0, stream>>>(w1, w1T, nullptr, 1024, 2048,
                                                           (long long)1024 * 2048,
                                                           (long long)2048 * 1024);
  tconv_kernel<false><<<dim3(32, 16, 8), 256, 0, stream>>>(w3, w3T, nullptr, 1024, 2048,
                                                           (long long)1024 * 2048,
                                                           (long long)2048 * 1024);
  gemm_kernel<2><<<dim3(32, 40, 1), 256, 0, stream>>>(t_bf, nullptr, w1T, w3T, nullptr, nullptr, G,
                                                      nullptr, idxb, wgtb, cnt, offs, tmap, 2048,
                                                      1024);
  tconv_kernel<false><<<dim3(16, 32, 8), 256, 0, stream>>>(w2, w2T, nullptr, 2048, 1024,
                                                           (long long)2048 * 1024,
                                                           (long long)1024 * 2048);
  gemm_kernel<3><<<dim3(16, 40, 1), 256, 0, stream>>>(G, nullptr, w2T, nullptr, out, nullptr,
                                                      nullptr, nullptr, idxb, wgtb, cnt, offs, tmap,
                                                      1024, 2048);
}